// Round 4
// baseline (681.044 us; speedup 1.0000x reference)
//
#include <hip/hip_runtime.h>
#include <stdint.h>

// Problem constants (from reference setup_inputs)
#define NQ      256        // D: number of query descriptors
#define NC      256        // C: descriptor dim
#define NDB     500000     // N: db rows
#define ROWLEN  257        // places_db row stride (256 dims + id)
#define MIN_SIM_F 0.8f
#define NMS_THR   0.8f
#define CAP     64         // candidate capacity per query
#define TILE    32         // db rows per GEMM tile (500000/32 = 15625 exact)
#define NTILES  (NDB / TILE)
#define BLK     512
#define GEMM_GRID 512      // 2 blocks/CU

typedef __bf16 bf16x8 __attribute__((ext_vector_type(8)));
typedef float  f32x4  __attribute__((ext_vector_type(4)));
// 4-byte-aligned variant for global loads at row*1028B offsets (rows are
// only dword-aligned; global_load_dwordx4 needs dword alignment only).
typedef float  f32x4u __attribute__((ext_vector_type(4), aligned(4)));

union BU { unsigned short u[8]; bf16x8 v; };

__device__ __forceinline__ unsigned short f2bf(float f) {
    uint32_t u = __float_as_uint(f);
    u += 0x7FFFu + ((u >> 16) & 1u);   // round-to-nearest-even
    return (unsigned short)(u >> 16);
}

// ---------------------------------------------------------------------------
// Kernel 0: zero the per-query candidate counters (ws is poisoned 0xAA)
// ---------------------------------------------------------------------------
__global__ void init_counts(int* cnt) { cnt[threadIdx.x] = 0; }

// ---------------------------------------------------------------------------
// Kernel 1: bf16-MFMA GEMM (q @ X^T) with >=MIN_SIM filter.
// 512 threads = 8 waves; wave w owns queries [w*32, w*32+32) as persistent
// register A-fragments (a[2][8] = 64 VGPR).
//
// R6 (this round): ISSUE-EARLY / WRITE-LATE PIPELINE (T14). R3-R5 all kept
// pipeline depth 1: loads issued ~250 cyc before their vmcnt drain against
// ~900 cyc HBM latency -> ~1300 exposed cyc/tile/wave, all 8 waves stalling
// together. New schedule, one-iteration register lookahead:
//   iter i: WRITE4(buf^1) from p   <- p loaded during iter i-1, already
//                                     drained by the barrier: ZERO-stall
//           LOAD4(tile i+2) -> p   <- flies across the whole MFMA phase
//           MFMA s0..7 on buf      (~600+ cyc of cover)
//           filter epilogue
//           __syncthreads()        <- compiler vmcnt(0) drain: ~300 cyc
//                                     exposed instead of ~1300
// LDS stays 2 buffers (33.8 KB, 2 blocks/CU). No sync-structure change
// (still plain __syncthreads once per tile) -> no race-lane risk.
// Budget: A 64 + acc 16 + p 16 + temps ~24 = ~120 < 128 cap. No spills.
// Global loads stay wave-contiguous (R5): round r -> wave w reads db row
// r*8+w, lane l takes floats 4l..4l+3 (one 1KB transaction per wave-load);
// id column (col 256) never loaded.
// mfma_f32_16x16x32_bf16 layouts (verified: absmax 0 in all prior rounds):
//   A: lane holds A[m=lane&15][k=(lane>>4)*8+j]
//   B: lane holds B[k=(lane>>4)*8+j][n=lane&15]
//   D: D[row=(lane>>4)*4+r][col=lane&15]
// ---------------------------------------------------------------------------
__global__ __launch_bounds__(BLK, 4) void gemm_filter(
    const float* __restrict__ q, const float* __restrict__ db,
    int* __restrict__ cnt, float* __restrict__ csim, int* __restrict__ cidx)
{
    // Row stride 264 bf16 = 528 B: every row 16B-aligned; ds_read_b128 start
    // banks spread over {0,4,..,28}, worst 2-way (free per m136).
    __shared__ __align__(16) unsigned short Bs[2][TILE][264];

    const int tid  = threadIdx.x;
    const int wave = tid >> 6;      // 0..7
    const int lane = tid & 63;
    const int quad = lane >> 4;
    const int l16  = lane & 15;

    // Persistent A fragments: wave w covers queries [w*32, w*32+32)
    bf16x8 a[2][8];
    #pragma unroll
    for (int f = 0; f < 2; ++f) {
        const int m = wave * 32 + f * 16 + l16;
        const float* qrow = q + m * NC;
        #pragma unroll
        for (int s = 0; s < 8; ++s) {
            const int k0 = s * 32 + quad * 8;
            const f32x4 v0 = *(const f32x4*)(qrow + k0);
            const f32x4 v1 = *(const f32x4*)(qrow + k0 + 4);
            BU u;
            #pragma unroll
            for (int j = 0; j < 4; ++j) {
                u.u[j]     = f2bf(v0[j]);
                u.u[4 + j] = f2bf(v1[j]);
            }
            a[f][s] = u.v;
        }
    }

    // Whole-tile prefetch: 16 floats/thread. Round r in {0..3}: wave w loads
    // db row r*8 + w, lane l takes floats 4l..4l+3 (contiguous 1KB / wave).
    f32x4 p0, p1, p2, p3;

    auto LOAD4 = [&](int tile) {
        const float* base = db + (size_t)tile * TILE * ROWLEN + (size_t)lane * 4;
        p0 = *(const f32x4u*)(base + (size_t)(wave)      * ROWLEN);
        p1 = *(const f32x4u*)(base + (size_t)(8 + wave)  * ROWLEN);
        p2 = *(const f32x4u*)(base + (size_t)(16 + wave) * ROWLEN);
        p3 = *(const f32x4u*)(base + (size_t)(24 + wave) * ROWLEN);
    };

    auto WRITE4 = [&](int nb) {
        union { unsigned short u[4]; uint2 v; } w0, w1, w2, w3;
        #pragma unroll
        for (int e = 0; e < 4; ++e) {
            w0.u[e] = f2bf(p0[e]);
            w1.u[e] = f2bf(p1[e]);
            w2.u[e] = f2bf(p2[e]);
            w3.u[e] = f2bf(p3[e]);
        }
        *(uint2*)&Bs[nb][wave][lane * 4]      = w0.v;   // ds_write_b64
        *(uint2*)&Bs[nb][8 + wave][lane * 4]  = w1.v;
        *(uint2*)&Bs[nb][16 + wave][lane * 4] = w2.v;
        *(uint2*)&Bs[nb][24 + wave][lane * 4] = w3.v;
    };

    auto COMPUTE = [&](int cb, int tile) {
        const f32x4 zero = {0.f, 0.f, 0.f, 0.f};
        f32x4 acc[2][2] = {{zero, zero}, {zero, zero}};
        #pragma unroll
        for (int s = 0; s < 8; ++s) {
            const bf16x8 b0 = *(const bf16x8*)&Bs[cb][l16][s * 32 + quad * 8];
            const bf16x8 b1 = *(const bf16x8*)&Bs[cb][16 + l16][s * 32 + quad * 8];
            acc[0][0] = __builtin_amdgcn_mfma_f32_16x16x32_bf16(a[0][s], b0, acc[0][0], 0, 0, 0);
            acc[1][0] = __builtin_amdgcn_mfma_f32_16x16x32_bf16(a[1][s], b0, acc[1][0], 0, 0, 0);
            acc[0][1] = __builtin_amdgcn_mfma_f32_16x16x32_bf16(a[0][s], b1, acc[0][1], 0, 0, 0);
            acc[1][1] = __builtin_amdgcn_mfma_f32_16x16x32_bf16(a[1][s], b1, acc[1][1], 0, 0, 0);
        }
        // Filter epilogue: wave-rare fast path (max sim in data ~0.38 << 0.8)
        float mx = acc[0][0][0];
        #pragma unroll
        for (int fm = 0; fm < 2; ++fm)
            #pragma unroll
            for (int h = 0; h < 2; ++h)
                #pragma unroll
                for (int rr = 0; rr < 4; ++rr) mx = fmaxf(mx, acc[fm][h][rr]);
        if (mx >= MIN_SIM_F) {
            #pragma unroll
            for (int fm = 0; fm < 2; ++fm) {
                #pragma unroll
                for (int h = 0; h < 2; ++h) {
                    #pragma unroll
                    for (int rr = 0; rr < 4; ++rr) {
                        const float sv = acc[fm][h][rr];
                        if (sv >= MIN_SIM_F) {
                            const int qi   = wave * 32 + fm * 16 + quad * 4 + rr;
                            const int rowg = tile * TILE + h * 16 + l16;
                            const int pos = atomicAdd(&cnt[qi], 1);
                            if (pos < CAP) {
                                csim[qi * CAP + pos] = sv;
                                cidx[qi * CAP + pos] = rowg;
                            }
                        }
                    }
                }
            }
        }
    };

    // Prologue: stage tile i0 into buf0; prefetch tile i1 into registers.
    int tile = blockIdx.x;
    LOAD4(tile);
    WRITE4(0);
    int nxt = tile + GEMM_GRID;
    bool havep = (nxt < NTILES);
    if (havep) LOAD4(nxt);            // p = tile i+1, drained by the barrier
    __syncthreads();
    int bi = 0;

    for (;;) {
        if (havep) WRITE4(bi ^ 1);    // zero-stall: p is a full iteration old
        const int  n2    = nxt + GEMM_GRID;
        const bool have2 = havep && (n2 < NTILES);
        if (have2) LOAD4(n2);         // flies across the whole MFMA phase
        COMPUTE(bi, tile);
        if (!havep) break;
        __syncthreads();              // drains n2 loads with ~600 cyc slack
        tile = nxt; nxt = n2; havep = have2; bi ^= 1;
    }
}

// ---------------------------------------------------------------------------
// Kernel 2: per-query top-10 + voting + NMS + outputs. One block, 256 threads.
// ---------------------------------------------------------------------------
__device__ __forceinline__ bool better(float s1, int i1, float s2, int i2) {
    return (s1 > s2) || (s1 == s2 && i1 < i2);   // lax.top_k tie-break
}

__global__ __launch_bounds__(256) void postprocess(
    const float* __restrict__ boxes, const float* __restrict__ db,
    const int* __restrict__ cnt, const float* __restrict__ csim,
    const int* __restrict__ cidx, float* __restrict__ out)
{
    __shared__ int   lab[NQ];
    __shared__ float area_s[NQ];
    __shared__ float bx[NQ][4];

    const int q = threadIdx.x;

    // ---- exact top-10 by (sim desc, idx asc) via insertion ----
    float s10[10]; int i10[10];
    int k = 0;
    int c = cnt[q]; if (c > CAP) c = CAP;
    for (int j = 0; j < c; ++j) {
        const float s = csim[q * CAP + j];
        const int   ix = cidx[q * CAP + j];
        int p;
        if (k < 10) { p = k; ++k; }
        else { if (!better(s, ix, s10[9], i10[9])) continue; p = 9; }
        while (p > 0 && better(s, ix, s10[p - 1], i10[p - 1])) {
            s10[p] = s10[p - 1]; i10[p] = i10[p - 1]; --p;
        }
        s10[p] = s; i10[p] = ix;
    }

    // ---- voting (all candidates already >= MIN_SIM) ----
    int vid[10];
    for (int j = 0; j < k; ++j) vid[j] = (int)db[(size_t)i10[j] * ROWLEN + (ROWLEN - 1)];
    int best_cnt = 0, best_id = 0x7fffffff;
    for (int j = 0; j < k; ++j) {
        int cj = 0;
        for (int l = 0; l < k; ++l) cj += (vid[l] == vid[j]) ? 1 : 0;
        if (cj > best_cnt || (cj == best_cnt && vid[j] < best_id)) { best_cnt = cj; best_id = vid[j]; }
    }
    const int lq = (best_cnt > 0) ? best_id : -1;   // MIN_VOTES=0
    lab[q] = lq;

    const float x1 = boxes[q * 4 + 0], y1 = boxes[q * 4 + 1];
    const float x2 = boxes[q * 4 + 2], y2 = boxes[q * 4 + 3];
    bx[q][0] = x1; bx[q][1] = y1; bx[q][2] = x2; bx[q][3] = y2;
    const float aq = (x2 - x1) * (y2 - y1);
    area_s[q] = aq;
    __syncthreads();

    // ---- NMS: remove q if exists p!=q, same label>=0, overlap>=thr, area_p <= area_q
    bool rem = false;
    if (lq >= 0) {
        for (int p = 0; p < NQ; ++p) {
            if (p == q || lab[p] != lq) continue;
            const float ap = area_s[p];
            if (ap > aq) continue;
            const float xi1 = fmaxf(x1, bx[p][0]);
            const float yi1 = fmaxf(y1, bx[p][1]);
            const float xi2 = fminf(x2, bx[p][2]);
            const float yi2 = fminf(y2, bx[p][3]);
            const float inter = fmaxf(xi2 - xi1, 0.f) * fmaxf(yi2 - yi1, 0.f);
            const float small = fminf(aq, ap);
            const float ov = (small > 0.f) ? inter / small : 0.f;
            if (ov >= NMS_THR) { rem = true; break; }
        }
    }
    const int lq2 = rem ? -1 : lq;

    // ---- sim_scores with final labels ----
    float score = 0.f;
    if (lq2 >= 0)
        for (int j = 0; j < k; ++j)
            if (vid[j] == lq2) score = fmaxf(score, s10[j]);

    // ---- outputs: [boxes 1024][sim_scores 256][results 256] as float32 ----
    for (int t = q; t < NQ * 4; t += NQ) out[t] = boxes[t];
    out[NQ * 4 + q] = score;
    out[NQ * 5 + q] = (float)lq2;
}

// ---------------------------------------------------------------------------
extern "C" void kernel_launch(void* const* d_in, const int* in_sizes, int n_in,
                              void* d_out, int out_size, void* d_ws, size_t ws_size,
                              hipStream_t stream) {
    const float* boxes = (const float*)d_in[0];   // final_boxes (256,4)
    const float* desc  = (const float*)d_in[1];   // descriptors (256,256)
    const float* db    = (const float*)d_in[2];   // places_db  (500000,257)
    float* out = (float*)d_out;

    int*   cnt  = (int*)d_ws;                                   // 256 ints
    float* csim = (float*)((char*)d_ws + 1024);                 // 256*CAP floats
    int*   cidx = (int*)((char*)d_ws + 1024 + NQ * CAP * 4);    // 256*CAP ints

    init_counts<<<1, 256, 0, stream>>>(cnt);
    gemm_filter<<<GEMM_GRID, BLK, 0, stream>>>(desc, db, cnt, csim, cidx);
    postprocess<<<1, 256, 0, stream>>>(boxes, db, cnt, csim, cidx, out);
}